// Round 9
// baseline (359.539 us; speedup 1.0000x reference)
//
#include <hip/hip_runtime.h>
#include <cstdint>
#include <cstddef>

#define N_    32
#define C_    256
#define H_    56
#define W_    56
#define HW_   (H_ * W_)      // 3136
#define NHW_  (N_ * HW_)     // 100352
#define COUT_ 256
#define EPS_  1e-4f
#define PW_   58             // padded width
#define PIMG_ (PW_ * PW_)    // 3364 padded pixels per image

// ---------------------------------------------------------------------------
// Kernel 1a: BN partial sums. 2048 blocks = (c, slice of 4 images).
// ---------------------------------------------------------------------------
__global__ void k_bn_partial(const float* __restrict__ x,
                             float* __restrict__ ps, float* __restrict__ pq) {
    const int c = blockIdx.x >> 3;
    const int s = blockIdx.x & 7;
    const int t = threadIdx.x;
    float sm = 0.f, sq = 0.f;
    for (int n = s * 4; n < s * 4 + 4; ++n) {
        const float4* p = (const float4*)(x + (size_t)(n * C_ + c) * HW_);
        for (int i = t; i < HW_ / 4; i += 256) {
            float4 v = p[i];
            sm += v.x + v.y + v.z + v.w;
            sq += v.x * v.x + v.y * v.y + v.z * v.z + v.w * v.w;
        }
    }
    __shared__ float ls[256], lq[256];
    ls[t] = sm; lq[t] = sq;
    __syncthreads();
    for (int off = 128; off >= 1; off >>= 1) {
        if (t < off) { ls[t] += ls[t + off]; lq[t] += lq[t + off]; }
        __syncthreads();
    }
    if (t == 0) { ps[s * C_ + c] = ls[0]; pq[s * C_ + c] = lq[0]; }
}

// ---------------------------------------------------------------------------
// Kernel 1b: finalize per-channel affine: xn = x*a[c] + bb[c]
// ---------------------------------------------------------------------------
__global__ void k_bn_final(const float* __restrict__ ps, const float* __restrict__ pq,
                           const float* __restrict__ gamma, const float* __restrict__ beta,
                           float* __restrict__ a, float* __restrict__ bb) {
    const int c = threadIdx.x;
    float sm = 0.f, sq = 0.f;
    for (int s = 0; s < 8; ++s) { sm += ps[s * C_ + c]; sq += pq[s * C_ + c]; }
    float mu   = sm * (1.f / NHW_);
    float var  = sq * (1.f / NHW_) - mu * mu;
    float rstd = rsqrtf(var + EPS_);
    float g    = gamma[c] * rstd;
    a[c]  = g;
    bb[c] = beta[c] - mu * g;
}

// ---------------------------------------------------------------------------
// Kernel 2: weight prep. alpha, bit-pack sign(W) into TAP-MAJOR layout
// wbits[wd][t][co] (for fixed (wd,t) the couts are contiguous -> one 64-B
// s_load burst covers a chunk of 8 couts in k_conv), and border table
// ctab[cls][co].
// ---------------------------------------------------------------------------
__global__ void k_wpack(const float* __restrict__ Wt, float* __restrict__ alpha,
                        uint64_t* __restrict__ wbits, int* __restrict__ ctab) {
    const int co = blockIdx.x;
    const int ci = threadIdx.x;
    const int lane = ci & 63, wave = ci >> 6;      // wave == channel-word wd
    const float* p = Wt + (size_t)(co * C_ + ci) * 9;
    float wv[9];
    float asum = 0.f;
#pragma unroll
    for (int t = 0; t < 9; ++t) { wv[t] = p[t]; asum += fabsf(wv[t]); }
    __shared__ int Pl[9];
    if (ci < 9) Pl[ci] = 0;
    __syncthreads();
#pragma unroll
    for (int t = 0; t < 9; ++t) {
        uint64_t mask = __ballot(wv[t] > 0.f);
        if (lane == 0) {
            wbits[((size_t)wave * 9 + t) * COUT_ + co] = mask;   // [wd][t][co]
            atomicAdd(&Pl[t], (int)__popcll(mask));
        }
    }
    __shared__ float red[256];
    red[ci] = asum;
    __syncthreads();                       // also publishes Pl
    for (int off = 128; off >= 1; off >>= 1) {
        if (ci < off) red[ci] += red[ci + off];
        __syncthreads();
    }
    if (ci == 0) alpha[co] = red[0] * (1.f / 2304.f);
    if (ci < 9) {
        const int rc = ci / 3, cc = ci % 3;
        unsigned m9 = (rc == 0 ? 0x007u : 0u) | (rc == 2 ? 0x1C0u : 0u)
                    | (cc == 0 ? 0x049u : 0u) | (cc == 2 ? 0x124u : 0u);
        int s = 0;
#pragma unroll
        for (int t = 0; t < 9; ++t)
            if ((m9 >> t) & 1) s += 2 * Pl[t] - 256;
        ctab[ci * 256 + co] = s;
    }
}

// ---------------------------------------------------------------------------
// Kernel 3: fused normalize + |xn| partial channel-mean + sign bit-pack into
// PLANAR padded layout xbits[wd][n][58][58] (borders pre-zeroed by memset).
// grid.y = which 64-channel word this block handles.
// ---------------------------------------------------------------------------
__global__ void k_mpack(const float* __restrict__ x, const float* __restrict__ a,
                        const float* __restrict__ bb, uint64_t* __restrict__ xbits,
                        float* __restrict__ m) {
    const int p = blockIdx.x * 256 + threadIdx.x;
    const int wd = blockIdx.y;          // 64-channel word index 0..3
    const int n = p / HW_;
    const int hw = p - n * HW_;
    const int h = hw / W_;
    const int w = hw - h * W_;
    const float* xp = x + (size_t)n * C_ * HW_ + (size_t)(wd * 64) * HW_ + hw;
    float macc = 0.f;
    uint64_t bw = 0;
#pragma unroll
    for (int j = 0; j < 64; ++j) {
        const int c = wd * 64 + j;
        float xn = fmaf(xp[(size_t)j * HW_], a[c], bb[c]);
        macc += fabsf(xn);
        bw |= (xn > 0.f) ? (1ull << j) : 0ull;
    }
    xbits[((size_t)wd * N_ + n) * PIMG_ + (size_t)(h + 1) * PW_ + (w + 1)] = bw;
    atomicAdd(&m[p], macc * (1.f / C_));
}

// ---------------------------------------------------------------------------
// Kernel 3b: 3x3 box filter (zero-padded, /9) on m -> beta_map
// ---------------------------------------------------------------------------
__global__ void k_box(const float* __restrict__ m, float* __restrict__ beta_map) {
    const int idx = blockIdx.x * 256 + threadIdx.x;
    if (idx >= NHW_) return;
    const int w = idx % W_;
    const int h = (idx / W_) % H_;
    const int n = idx / HW_;
    const float* mp = m + (size_t)n * HW_;
    float s = 0.f;
#pragma unroll
    for (int dh = 0; dh < 3; ++dh) {
        int ih = h + dh - 1;
        if (ih < 0 || ih >= H_) continue;
#pragma unroll
        for (int dw = 0; dw < 3; ++dw) {
            int iw = w + dw - 1;
            if (iw < 0 || iw >= W_) continue;
            s += mp[ih * W_ + iw];
        }
    }
    beta_map[idx] = s * (1.f / 9.f);
}

// ---------------------------------------------------------------------------
// Kernel 4: binary conv, CHUNK-8 form. r8 diagnosis: VGPR_Count=32 with
// occupancy 51% (4 waves/SIMD) == acc[32] parked in AGPRs (~128 unified
// regs/wave), +4 copy ops per XNP -> measured 10.4K VALU/thread vs 5.2K
// clean. Pattern r0-r8: ANY array >= ~32 regs live across a long loop gets
// parked. Fix: chunk couts by 8. acc[8] is the only persistent array; taps
// inner; window streamed one u64 at a time via VOLATILE loads (volatile
// blocks LICM from hoisting the 36 loop-invariant window loads out of the
// chunk loop, which would recreate the 72-reg blob). Per chunk x tap:
// 8-B window load + 64-B contiguous s_load (8 weights, [wd][t][co] layout)
// + 8 XNP asm blocks. Live set ~32 VGPR; (256,8) budget 64.
// ---------------------------------------------------------------------------
#define XNP(ACC, X64, W64) do {                                   \
    uint32_t _wl = (uint32_t)(W64), _wh = (uint32_t)((W64) >> 32); \
    uint32_t _xl = (uint32_t)(X64), _xh = (uint32_t)((X64) >> 32); \
    uint32_t _t0, _t1;                                             \
    asm("v_xor_b32 %0, %3, %5\n\t"                                 \
        "v_xor_b32 %1, %4, %6\n\t"                                 \
        "v_bcnt_u32_b32 %2, %0, %2\n\t"                            \
        "v_bcnt_u32_b32 %2, %1, %2"                                \
        : "=&v"(_t0), "=&v"(_t1), "+v"(ACC)                        \
        : "s"(_wl), "s"(_wh), "v"(_xl), "v"(_xh));                 \
} while (0)

__global__ void __launch_bounds__(256, 8)
k_conv(const uint64_t* __restrict__ xbits, const uint64_t* __restrict__ wbits,
       const int* __restrict__ ctab, const float* __restrict__ beta_map,
       const float* __restrict__ alpha, const float* __restrict__ bias,
       float* __restrict__ out) {
    const int p   = blockIdx.x * 256 + (int)threadIdx.x;  // flat pixel
    const int grp = blockIdx.y;                            // cout group of 64
    const int n  = p / HW_;
    const int hw = p - n * HW_;
    const int h  = hw / W_;
    const int w  = hw - h * W_;

    const int rowcls = (h == 0) ? 0 : ((h == H_ - 1) ? 2 : 1);
    const int colcls = (w == 0) ? 0 : ((w == W_ - 1) ? 2 : 1);
    const int* crow = ctab + (rowcls * 3 + colcls) * 256 + grp * 64;
    const float bm = beta_map[p];
    float* op = out + (size_t)n * COUT_ * HW_ + (size_t)(grp * 64) * HW_ + hw;

#pragma unroll 1
    for (int ch = 0; ch < 8; ++ch) {               // chunk of 8 couts
        int acc[8];
#pragma unroll
        for (int i = 0; i < 8; ++i) acc[i] = 0;

#pragma unroll 1
        for (int wd = 0; wd < 4; ++wd) {
            const uint64_t* xp = xbits + ((size_t)wd * N_ + n) * PIMG_
                                       + (size_t)h * PW_ + w;
            const uint64_t* wq = wbits + (size_t)wd * 9 * COUT_ + grp * 64 + ch * 8;
#pragma unroll 3
            for (int t = 0; t < 9; ++t) {
                // volatile: forbid hoisting/CSE across chunks (would rebuild
                // the 72-reg window blob that triggers AGPR parking)
                const uint64_t xv = *(const volatile uint64_t*)(xp + (t / 3) * PW_ + (t % 3));
                const uint64_t* wr = wq + t * COUT_;   // wave-uniform, 64 B contiguous
#pragma unroll
                for (int i = 0; i < 8; ++i) XNP(acc[i], xv, wr[i]);
            }
        }

#pragma unroll
        for (int i = 0; i < 8; ++i) {
            const int coi = ch * 8 + i;
            const int co  = grp * 64 + coi;
            const int dot = 2304 - 2 * acc[i] + crow[coi];
            float o = ((float)dot + bias[co]) * bm * alpha[co];
            o = fmaxf(o, 0.f);
            op[(size_t)coi * HW_] = o;
        }
    }
}

// ---------------------------------------------------------------------------
// Workspace layout (bytes):
//   ps       @ 0        8192
//   pq       @ 8192     8192
//   a        @ 16384    1024
//   bb       @ 17408    1024
//   alpha    @ 18432    1024
//   ctab     @ 19456    9216
//   wbits    @ 28672    73728     ([wd][t][co] u64, tap-major)
//   xbits    @ 102400   3444736   (planar [wd][32][58][58] u64, memset 0)
//   m        @ 3547136  401408    (zeroed via memset; atomic-accumulated)
//   beta_map @ 3948544  401408
//   total    4349952
// ---------------------------------------------------------------------------
extern "C" void kernel_launch(void* const* d_in, const int* in_sizes, int n_in,
                              void* d_out, int out_size, void* d_ws, size_t ws_size,
                              hipStream_t stream) {
    (void)in_sizes; (void)n_in; (void)out_size; (void)ws_size;
    const float* x     = (const float*)d_in[0];
    const float* gamma = (const float*)d_in[1];
    const float* betab = (const float*)d_in[2];
    const float* Wt    = (const float*)d_in[3];
    const float* b     = (const float*)d_in[4];
    float* out = (float*)d_out;

    uint8_t* base = (uint8_t*)d_ws;
    float*    ps       = (float*)(base + 0);
    float*    pq       = (float*)(base + 8192);
    float*    a        = (float*)(base + 16384);
    float*    bb       = (float*)(base + 17408);
    float*    alpha    = (float*)(base + 18432);
    int*      ctab     = (int*)(base + 19456);
    uint64_t* wbits    = (uint64_t*)(base + 28672);
    uint64_t* xbits    = (uint64_t*)(base + 102400);
    float*    m        = (float*)(base + 3547136);
    float*    beta_map = (float*)(base + 3948544);

    k_bn_partial<<<2048, 256, 0, stream>>>(x, ps, pq);
    k_bn_final<<<1, 256, 0, stream>>>(ps, pq, gamma, betab, a, bb);
    k_wpack<<<COUT_, 256, 0, stream>>>(Wt, alpha, wbits, ctab);
    hipMemsetAsync(xbits, 0, (size_t)N_ * PIMG_ * 4 * sizeof(uint64_t), stream);
    hipMemsetAsync(m, 0, (size_t)NHW_ * sizeof(float), stream);
    k_mpack<<<dim3(NHW_ / 256, 4), 256, 0, stream>>>(x, a, bb, xbits, m);
    k_box<<<(NHW_ + 255) / 256, 256, 0, stream>>>(m, beta_map);
    k_conv<<<dim3(NHW_ / 256, 4), 256, 0, stream>>>(xbits, wbits, ctab, beta_map, alpha, b, out);
}

// Round 10
// 299.378 us; speedup vs baseline: 1.2010x; 1.2010x over previous
//
#include <hip/hip_runtime.h>
#include <cstdint>
#include <cstddef>

#define N_    32
#define C_    256
#define H_    56
#define W_    56
#define HW_   (H_ * W_)      // 3136
#define NHW_  (N_ * HW_)     // 100352
#define COUT_ 256
#define EPS_  1e-4f
#define PW_   58             // padded width
#define PIMG_ (PW_ * PW_)    // 3364 padded pixels per image

// ---------------------------------------------------------------------------
// Kernel 1a: BN partial sums. 2048 blocks = (c, slice of 4 images).
// ---------------------------------------------------------------------------
__global__ void k_bn_partial(const float* __restrict__ x,
                             float* __restrict__ ps, float* __restrict__ pq) {
    const int c = blockIdx.x >> 3;
    const int s = blockIdx.x & 7;
    const int t = threadIdx.x;
    float sm = 0.f, sq = 0.f;
    for (int n = s * 4; n < s * 4 + 4; ++n) {
        const float4* p = (const float4*)(x + (size_t)(n * C_ + c) * HW_);
        for (int i = t; i < HW_ / 4; i += 256) {
            float4 v = p[i];
            sm += v.x + v.y + v.z + v.w;
            sq += v.x * v.x + v.y * v.y + v.z * v.z + v.w * v.w;
        }
    }
    __shared__ float ls[256], lq[256];
    ls[t] = sm; lq[t] = sq;
    __syncthreads();
    for (int off = 128; off >= 1; off >>= 1) {
        if (t < off) { ls[t] += ls[t + off]; lq[t] += lq[t + off]; }
        __syncthreads();
    }
    if (t == 0) { ps[s * C_ + c] = ls[0]; pq[s * C_ + c] = lq[0]; }
}

// ---------------------------------------------------------------------------
// Kernel 1b: finalize per-channel affine: xn = x*a[c] + bb[c]
// ---------------------------------------------------------------------------
__global__ void k_bn_final(const float* __restrict__ ps, const float* __restrict__ pq,
                           const float* __restrict__ gamma, const float* __restrict__ beta,
                           float* __restrict__ a, float* __restrict__ bb) {
    const int c = threadIdx.x;
    float sm = 0.f, sq = 0.f;
    for (int s = 0; s < 8; ++s) { sm += ps[s * C_ + c]; sq += pq[s * C_ + c]; }
    float mu   = sm * (1.f / NHW_);
    float var  = sq * (1.f / NHW_) - mu * mu;
    float rstd = rsqrtf(var + EPS_);
    float g    = gamma[c] * rstd;
    a[c]  = g;
    bb[c] = beta[c] - mu * g;
}

// ---------------------------------------------------------------------------
// Kernel 2: weight prep. alpha, bit-pack sign(W) into TAP-MAJOR layout
// wbits[wd][t][co] (for fixed (wd,t) the couts are contiguous -> one 64-B
// s_load burst covers a group of 8 couts in k_conv), and border table
// ctab[cls][co].
// ---------------------------------------------------------------------------
__global__ void k_wpack(const float* __restrict__ Wt, float* __restrict__ alpha,
                        uint64_t* __restrict__ wbits, int* __restrict__ ctab) {
    const int co = blockIdx.x;
    const int ci = threadIdx.x;
    const int lane = ci & 63, wave = ci >> 6;      // wave == channel-word wd
    const float* p = Wt + (size_t)(co * C_ + ci) * 9;
    float wv[9];
    float asum = 0.f;
#pragma unroll
    for (int t = 0; t < 9; ++t) { wv[t] = p[t]; asum += fabsf(wv[t]); }
    __shared__ int Pl[9];
    if (ci < 9) Pl[ci] = 0;
    __syncthreads();
#pragma unroll
    for (int t = 0; t < 9; ++t) {
        uint64_t mask = __ballot(wv[t] > 0.f);
        if (lane == 0) {
            wbits[((size_t)wave * 9 + t) * COUT_ + co] = mask;   // [wd][t][co]
            atomicAdd(&Pl[t], (int)__popcll(mask));
        }
    }
    __shared__ float red[256];
    red[ci] = asum;
    __syncthreads();                       // also publishes Pl
    for (int off = 128; off >= 1; off >>= 1) {
        if (ci < off) red[ci] += red[ci + off];
        __syncthreads();
    }
    if (ci == 0) alpha[co] = red[0] * (1.f / 2304.f);
    if (ci < 9) {
        const int rc = ci / 3, cc = ci % 3;
        unsigned m9 = (rc == 0 ? 0x007u : 0u) | (rc == 2 ? 0x1C0u : 0u)
                    | (cc == 0 ? 0x049u : 0u) | (cc == 2 ? 0x124u : 0u);
        int s = 0;
#pragma unroll
        for (int t = 0; t < 9; ++t)
            if ((m9 >> t) & 1) s += 2 * Pl[t] - 256;
        ctab[ci * 256 + co] = s;
    }
}

// ---------------------------------------------------------------------------
// Kernel 3: fused normalize + |xn| partial channel-mean + sign bit-pack into
// PLANAR padded layout xbits[wd][n][58][58] (borders pre-zeroed by memset).
// grid.y = which 64-channel word this block handles.
// ---------------------------------------------------------------------------
__global__ void k_mpack(const float* __restrict__ x, const float* __restrict__ a,
                        const float* __restrict__ bb, uint64_t* __restrict__ xbits,
                        float* __restrict__ m) {
    const int p = blockIdx.x * 256 + threadIdx.x;
    const int wd = blockIdx.y;          // 64-channel word index 0..3
    const int n = p / HW_;
    const int hw = p - n * HW_;
    const int h = hw / W_;
    const int w = hw - h * W_;
    const float* xp = x + (size_t)n * C_ * HW_ + (size_t)(wd * 64) * HW_ + hw;
    float macc = 0.f;
    uint64_t bw = 0;
#pragma unroll
    for (int j = 0; j < 64; ++j) {
        const int c = wd * 64 + j;
        float xn = fmaf(xp[(size_t)j * HW_], a[c], bb[c]);
        macc += fabsf(xn);
        bw |= (xn > 0.f) ? (1ull << j) : 0ull;
    }
    xbits[((size_t)wd * N_ + n) * PIMG_ + (size_t)(h + 1) * PW_ + (w + 1)] = bw;
    atomicAdd(&m[p], macc * (1.f / C_));
}

// ---------------------------------------------------------------------------
// Kernel 3b: 3x3 box filter (zero-padded, /9) on m -> beta_map
// ---------------------------------------------------------------------------
__global__ void k_box(const float* __restrict__ m, float* __restrict__ beta_map) {
    const int idx = blockIdx.x * 256 + threadIdx.x;
    if (idx >= NHW_) return;
    const int w = idx % W_;
    const int h = (idx / W_) % H_;
    const int n = idx / HW_;
    const float* mp = m + (size_t)n * HW_;
    float s = 0.f;
#pragma unroll
    for (int dh = 0; dh < 3; ++dh) {
        int ih = h + dh - 1;
        if (ih < 0 || ih >= H_) continue;
#pragma unroll
        for (int dw = 0; dw < 3; ++dw) {
            int iw = w + dw - 1;
            if (iw < 0 || iw >= W_) continue;
            s += mp[ih * W_ + iw];
        }
    }
    beta_map[idx] = s * (1.f / 9.f);
}

// ---------------------------------------------------------------------------
// Kernel 4: binary conv, PIXEL-PAIR form. Model correction from r7-r9: the
// reported VALUBusy uses gfx94x formulas (4-cyc wave64 issue) on a SIMD-32
// chip -> overstates ~2x. Real r7 profile: ~53 us VALU issue (== the 144
// ops/output floor, the asm core is already optimal) + ~75 us STALL. The
// stall: each 288-B wave-uniform weight s_load feeds only 144 VALU with
// ~3 waves/SIMD of cover. Fixes, keeping the proven XNP asm core:
//  - P=2 adjacent pixels/thread: one weight s_load feeds 32 XNP (2x
//    amortization); window row shared via 4-wide segment loads (16B
//    aligned ulonglong2 x2); outputs stored as coalesced float2.
//  - 8-cout groups (grid.y=32) -> 6272 blocks (24/CU) and a small live
//    set: acc0[8]+acc1[8]=16 regs + 8-reg row segment. No array big
//    enough to trigger the r0-r8 AGPR-parking.
//  - 16 independent bcnt chains pipeline the VALU latency.
// ---------------------------------------------------------------------------
#define XNP(ACC, X64, W64) do {                                   \
    uint32_t _wl = (uint32_t)(W64), _wh = (uint32_t)((W64) >> 32); \
    uint32_t _xl = (uint32_t)(X64), _xh = (uint32_t)((X64) >> 32); \
    uint32_t _t0, _t1;                                             \
    asm("v_xor_b32 %0, %3, %5\n\t"                                 \
        "v_xor_b32 %1, %4, %6\n\t"                                 \
        "v_bcnt_u32_b32 %2, %0, %2\n\t"                            \
        "v_bcnt_u32_b32 %2, %1, %2"                                \
        : "=&v"(_t0), "=&v"(_t1), "+v"(ACC)                        \
        : "s"(_wl), "s"(_wh), "v"(_xl), "v"(_xh));                 \
} while (0)

__global__ void __launch_bounds__(256, 8)
k_conv(const uint64_t* __restrict__ xbits, const uint64_t* __restrict__ wbits,
       const int* __restrict__ ctab, const float* __restrict__ beta_map,
       const float* __restrict__ alpha, const float* __restrict__ bias,
       float* __restrict__ out) {
    const int idx = blockIdx.x * 512 + (int)threadIdx.x * 2;  // even pixel
    const int grp = blockIdx.y;                                // cout group of 8
    const int n  = idx / HW_;
    const int hw = idx - n * HW_;
    const int h  = hw / W_;
    const int w  = hw - h * W_;      // even; pair (w, w+1) never straddles a row

    int acc0[8], acc1[8];
#pragma unroll
    for (int i = 0; i < 8; ++i) { acc0[i] = 0; acc1[i] = 0; }

#pragma unroll 1
    for (int wd = 0; wd < 4; ++wd) {
        const uint64_t* xp = xbits + ((size_t)wd * N_ + n) * PIMG_
                                   + (size_t)h * PW_ + w;
        const uint64_t* wq = wbits + (size_t)wd * 9 * COUT_ + grp * 8;
#pragma unroll
        for (int r = 0; r < 3; ++r) {
            // 4-wide row segment covers both pixels' 3 taps (16-B aligned:
            // w even, PW even, plane base 16-B aligned)
            const ulonglong2* q = (const ulonglong2*)(xp + r * PW_);
            const ulonglong2 qa = q[0], qb = q[1];
            const uint64_t xv[4] = { qa.x, qa.y, qb.x, qb.y };
#pragma unroll
            for (int c = 0; c < 3; ++c) {
                const uint64_t* wr = wq + (r * 3 + c) * COUT_;  // 64 B contiguous
#pragma unroll
                for (int i = 0; i < 8; ++i) {
                    XNP(acc0[i], xv[c],     wr[i]);
                    XNP(acc1[i], xv[c + 1], wr[i]);
                }
            }
        }
    }

    const int rowcls  = (h == 0) ? 0 : ((h == H_ - 1) ? 2 : 1);
    const int colcls0 = (w == 0) ? 0 : 1;              // w even -> never 55
    const int colcls1 = (w + 1 == W_ - 1) ? 2 : 1;     // w+1 odd -> never 0
    const int* crow0 = ctab + (rowcls * 3 + colcls0) * 256 + grp * 8;
    const int* crow1 = ctab + (rowcls * 3 + colcls1) * 256 + grp * 8;
    const float bm0 = beta_map[idx];
    const float bm1 = beta_map[idx + 1];
    float* op = out + (size_t)n * COUT_ * HW_ + (size_t)(grp * 8) * HW_ + hw;

#pragma unroll
    for (int i = 0; i < 8; ++i) {
        const int co = grp * 8 + i;
        const float al = alpha[co], bi = bias[co];
        const int d0 = 2304 - 2 * acc0[i] + crow0[i];
        const int d1 = 2304 - 2 * acc1[i] + crow1[i];
        const float o0 = fmaxf(((float)d0 + bi) * bm0 * al, 0.f);
        const float o1 = fmaxf(((float)d1 + bi) * bm1 * al, 0.f);
        *(float2*)(op + (size_t)i * HW_) = make_float2(o0, o1);
    }
}

// ---------------------------------------------------------------------------
// Workspace layout (bytes):
//   ps       @ 0        8192
//   pq       @ 8192     8192
//   a        @ 16384    1024
//   bb       @ 17408    1024
//   alpha    @ 18432    1024
//   ctab     @ 19456    9216
//   wbits    @ 28672    73728     ([wd][t][co] u64, tap-major)
//   xbits    @ 102400   3444736   (planar [wd][32][58][58] u64, memset 0)
//   m        @ 3547136  401408    (zeroed via memset; atomic-accumulated)
//   beta_map @ 3948544  401408
//   total    4349952
// ---------------------------------------------------------------------------
extern "C" void kernel_launch(void* const* d_in, const int* in_sizes, int n_in,
                              void* d_out, int out_size, void* d_ws, size_t ws_size,
                              hipStream_t stream) {
    (void)in_sizes; (void)n_in; (void)out_size; (void)ws_size;
    const float* x     = (const float*)d_in[0];
    const float* gamma = (const float*)d_in[1];
    const float* betab = (const float*)d_in[2];
    const float* Wt    = (const float*)d_in[3];
    const float* b     = (const float*)d_in[4];
    float* out = (float*)d_out;

    uint8_t* base = (uint8_t*)d_ws;
    float*    ps       = (float*)(base + 0);
    float*    pq       = (float*)(base + 8192);
    float*    a        = (float*)(base + 16384);
    float*    bb       = (float*)(base + 17408);
    float*    alpha    = (float*)(base + 18432);
    int*      ctab     = (int*)(base + 19456);
    uint64_t* wbits    = (uint64_t*)(base + 28672);
    uint64_t* xbits    = (uint64_t*)(base + 102400);
    float*    m        = (float*)(base + 3547136);
    float*    beta_map = (float*)(base + 3948544);

    k_bn_partial<<<2048, 256, 0, stream>>>(x, ps, pq);
    k_bn_final<<<1, 256, 0, stream>>>(ps, pq, gamma, betab, a, bb);
    k_wpack<<<COUT_, 256, 0, stream>>>(Wt, alpha, wbits, ctab);
    hipMemsetAsync(xbits, 0, (size_t)N_ * PIMG_ * 4 * sizeof(uint64_t), stream);
    hipMemsetAsync(m, 0, (size_t)NHW_ * sizeof(float), stream);
    k_mpack<<<dim3(NHW_ / 256, 4), 256, 0, stream>>>(x, a, bb, xbits, m);
    k_box<<<(NHW_ + 255) / 256, 256, 0, stream>>>(m, beta_map);
    k_conv<<<dim3(NHW_ / 512, 32), 256, 0, stream>>>(xbits, wbits, ctab, beta_map, alpha, b, out);
}